// Round 3
// baseline (211.127 us; speedup 1.0000x reference)
//
#include <hip/hip_runtime.h>
#include <hip/hip_bf16.h>
#include <stdint.h>

// Problem constants (from reference setup_inputs)
#define BATCH 8
#define TC 2048   // M
#define TQ 1024   // K
#define DD 1024   // N

typedef __attribute__((ext_vector_type(8))) __bf16 bf16x8;
typedef __attribute__((ext_vector_type(4))) float f32x4;
typedef __attribute__((ext_vector_type(8))) ushort ushort8v;

__device__ __forceinline__ ushort f2bf(float f) {
    uint32_t u = __float_as_uint(f);
    uint32_t r = (u + 0x7fffu + ((u >> 16) & 1u)) >> 16;  // RNE
    return (ushort)r;
}

// ---------------------------------------------------------------------------
// Kernel 1: row stats.  One wave per 2 rows (ILP-2: 8 float4 loads in flight
// per wave, 0 LDS, ~40 VGPR -> full 32-wave occupancy).  Reduction trees are
// BIT-IDENTICAL to the old prep softmax (same per-lane layout, same fmax tree,
// same (e0+e1)+(e2+e3) sum order, same shfl_xor butterfly) so the downstream
// fused attn values are bit-identical to the previous passing kernel.
// Writes stats[row] = {m, 1/s} (float2); lane 0 stores both rows as one f4.
// ---------------------------------------------------------------------------
__global__ __launch_bounds__(256) void rowstats(const float* __restrict__ sim,
                                                float2* __restrict__ stats) {
    const int t = threadIdx.x;
    const int wid = t >> 6, lane = t & 63;
    const int r0 = blockIdx.x * 8 + wid * 2;

    const float4* s0 = (const float4*)(sim + (size_t)r0 * TQ);
    const float4* s1 = (const float4*)(sim + (size_t)(r0 + 1) * TQ);

    float4 x0[4], x1[4];
    #pragma unroll
    for (int j = 0; j < 4; j++) { x0[j] = s0[lane + 64 * j]; x1[j] = s1[lane + 64 * j]; }

    float m0 = -INFINITY, m1 = -INFINITY;
    #pragma unroll
    for (int j = 0; j < 4; j++) {
        m0 = fmaxf(m0, fmaxf(fmaxf(x0[j].x, x0[j].y), fmaxf(x0[j].z, x0[j].w)));
        m1 = fmaxf(m1, fmaxf(fmaxf(x1[j].x, x1[j].y), fmaxf(x1[j].z, x1[j].w)));
    }
    #pragma unroll
    for (int o = 32; o >= 1; o >>= 1) {
        m0 = fmaxf(m0, __shfl_xor(m0, o));
        m1 = fmaxf(m1, __shfl_xor(m1, o));
    }

    const float L2E = 1.4426950408889634f;
    float sa = 0.f, sb = 0.f;
    #pragma unroll
    for (int j = 0; j < 4; j++) {
        {
            float e0 = exp2f((x0[j].x - m0) * L2E);
            float e1 = exp2f((x0[j].y - m0) * L2E);
            float e2 = exp2f((x0[j].z - m0) * L2E);
            float e3 = exp2f((x0[j].w - m0) * L2E);
            sa += (e0 + e1) + (e2 + e3);
        }
        {
            float e0 = exp2f((x1[j].x - m1) * L2E);
            float e1 = exp2f((x1[j].y - m1) * L2E);
            float e2 = exp2f((x1[j].z - m1) * L2E);
            float e3 = exp2f((x1[j].w - m1) * L2E);
            sb += (e0 + e1) + (e2 + e3);
        }
    }
    #pragma unroll
    for (int o = 32; o >= 1; o >>= 1) {
        sa += __shfl_xor(sa, o);
        sb += __shfl_xor(sb, o);
    }

    if (lane == 0) {
        float4 out = make_float4(m0, 1.0f / sa, m1, 1.0f / sb);
        *(float4*)&stats[r0] = out;   // r0 even -> 16B aligned
    }
}

// ---------------------------------------------------------------------------
// Kernel 2: transpose+cast  qencode [b][q][d] fp32 -> qt [b][d][q] bf16.
// 64q x 128d tile per block (1024 blocks).  8 float4 in flight per thread;
// output packs ushort8 (16B) with 8 lanes covering 64 contiguous q -> 128B
// coalesced store segments.  LDS stride 133 -> output column reads are 2-way
// bank aliased (free, m136); input scalar writes 4-way (minor).
// ---------------------------------------------------------------------------
__global__ __launch_bounds__(256) void transp(const float* __restrict__ qen,
                                              ushort* __restrict__ qt) {
    __shared__ float tile[64][133];
    const int t = threadIdx.x;
    const int bid = blockIdx.x;
    const int b = bid >> 7;             // 128 tiles per batch (16 q x 8 d)
    const int rem = bid & 127;
    const int q0 = (rem >> 3) * 64;
    const int d0 = (rem & 7) * 128;

    const int r0 = t >> 5;              // 0..7
    const int cf = (t & 31) * 4;        // 0..124

    float4 v[8];
    #pragma unroll
    for (int it = 0; it < 8; it++)
        v[it] = *(const float4*)(qen + ((size_t)b * TQ + q0 + r0 + it * 8) * DD + d0 + cf);
    #pragma unroll
    for (int it = 0; it < 8; it++) {
        tile[r0 + it * 8][cf + 0] = v[it].x;
        tile[r0 + it * 8][cf + 1] = v[it].y;
        tile[r0 + it * 8][cf + 2] = v[it].z;
        tile[r0 + it * 8][cf + 3] = v[it].w;
    }
    __syncthreads();

    const int q8 = (t & 7) * 8;         // 0..56
    const int dbase = t >> 3;           // 0..31
    #pragma unroll
    for (int j2 = 0; j2 < 4; j2++) {
        const int d = dbase + 32 * j2;
        ushort8v pk;
        #pragma unroll
        for (int j = 0; j < 8; j++) pk[j] = f2bf(tile[q8 + j][d]);
        *(ushort8v*)(qt + ((size_t)b * DD + d0 + d) * TQ + q0 + q8) = pk;
    }
}

// ---------------------------------------------------------------------------
// Kernel 3: fused GEMM  C[b] = softmax(S[b]) x Bt[b]^T.  Structure is the
// PROVEN R0 128x128 kernel (43.6us) unchanged except A-staging: instead of
// global_load_lds from a materialized attn, each thread loads 8 fp32 of sim
// (L3-resident after rowstats), applies exp2((x-m)*L2E)*inv (bit-identical to
// old prep), packs bf16, and ds_write_b128 to the SAME swizzled LDS slot:
//   row = i*32 + w*8 + (lane>>3), slot chunk = lane&7 holding global chunk
//   (lane&7)^(row&7)  ->  ushort idx = i*2048 + w*512 + lane*8.
// Fragment reads / MFMA order / epilogue untouched -> same numerics.
// Saves the 32MB attn write + 32MB read and the old prep's store phase.
// ---------------------------------------------------------------------------
__global__ __launch_bounds__(256, 2) void gemm_fused(const float* __restrict__ S,
                                                     const float2* __restrict__ st,
                                                     const ushort* __restrict__ Bt,
                                                     float* __restrict__ C) {
    __shared__ __align__(16) ushort As[128 * 64];   // 16 KiB
    __shared__ __align__(16) ushort Bs[128 * 64];   // 16 KiB

    const int flat = blockIdx.x;
    const int b = flat >> 7;          // batch
    const int rem = flat & 127;       // 16 m-tiles x 8 n-tiles
    const int group = rem >> 5;       // 4 groups of 32 blocks
    const int mi_t = group * 4 + (rem & 3);
    const int ni_t = (rem >> 2) & 7;
    const int tm0 = mi_t * 128;
    const int tn0 = ni_t * 128;

    const float* Sb = S + (size_t)b * TC * TQ;
    const ushort* Bb = Bt + (size_t)b * DD * TQ;
    float* Cb = C + (size_t)b * TC * DD;

    const int t = threadIdx.x;
    const int w = t >> 6, lane = t & 63;
    const int quad = lane >> 4, l16 = lane & 15;
    const int wm = (w >> 1) * 64, wn = (w & 1) * 64;

    f32x4 acc[4][4];
    #pragma unroll
    for (int i = 0; i < 4; i++)
        #pragma unroll
        for (int j = 0; j < 4; j++) acc[i][j] = (f32x4){0.f, 0.f, 0.f, 0.f};

    // staging ids (identical to R0): row = i*32 + srow; k chunk sk (swizzled)
    const int srow = w * 8 + (lane >> 3);
    const int sk = ((lane & 7) ^ (lane >> 3)) * 8;   // element offset in k
    const int rkey = l16 & 7;

    const float L2E = 1.4426950408889634f;

    // per-thread row stats for the 4 rows this thread stages (constant over kk)
    float2 stv[4];
    #pragma unroll
    for (int i = 0; i < 4; i++)
        stv[i] = st[(size_t)b * TC + tm0 + i * 32 + srow];

    for (int kk = 0; kk < TQ; kk += 64) {
        // ---- A: issue 8 fp32 loads (2 float4 x 4 rows) ----
        float4 xa[4][2];
        #pragma unroll
        for (int i = 0; i < 4; i++) {
            const float* g = Sb + (size_t)(tm0 + i * 32 + srow) * TQ + kk + sk;
            xa[i][0] = *(const float4*)g;
            xa[i][1] = *(const float4*)(g + 4);
        }
        // ---- B: global_load_lds, unchanged from R0 ----
        #pragma unroll
        for (int i = 0; i < 4; i++) {
            const ushort* gb = Bb + (size_t)(tn0 + i * 32 + srow) * TQ + kk + sk;
            char* lb = (char*)Bs + i * 4096 + w * 1024;
            __builtin_amdgcn_global_load_lds(
                (const __attribute__((address_space(1))) void*)gb,
                (__attribute__((address_space(3))) void*)lb, 16, 0, 0);
        }
        // ---- A: softmax-on-the-fly, pack, swizzled ds_write_b128 ----
        #pragma unroll
        for (int i = 0; i < 4; i++) {
            const float mm = stv[i].x, iv = stv[i].y;
            ushort8v pk;
            pk[0] = f2bf(exp2f((xa[i][0].x - mm) * L2E) * iv);
            pk[1] = f2bf(exp2f((xa[i][0].y - mm) * L2E) * iv);
            pk[2] = f2bf(exp2f((xa[i][0].z - mm) * L2E) * iv);
            pk[3] = f2bf(exp2f((xa[i][0].w - mm) * L2E) * iv);
            pk[4] = f2bf(exp2f((xa[i][1].x - mm) * L2E) * iv);
            pk[5] = f2bf(exp2f((xa[i][1].y - mm) * L2E) * iv);
            pk[6] = f2bf(exp2f((xa[i][1].z - mm) * L2E) * iv);
            pk[7] = f2bf(exp2f((xa[i][1].w - mm) * L2E) * iv);
            *(ushort8v*)&As[i * 2048 + w * 512 + lane * 8] = pk;
        }
        __syncthreads();

        #pragma unroll
        for (int s = 0; s < 2; s++) {
            const int rswz = ((s * 4 + quad) ^ rkey) * 8;   // ushort offset
            bf16x8 af[4], bfr[4];
            #pragma unroll
            for (int mi = 0; mi < 4; mi++)
                af[mi] = *(const bf16x8*)&As[(wm + mi * 16 + l16) * 64 + rswz];
            #pragma unroll
            for (int ni = 0; ni < 4; ni++)
                bfr[ni] = *(const bf16x8*)&Bs[(wn + ni * 16 + l16) * 64 + rswz];

            #pragma unroll
            for (int mi = 0; mi < 4; mi++)
                #pragma unroll
                for (int ni = 0; ni < 4; ni++)
                    acc[mi][ni] = __builtin_amdgcn_mfma_f32_16x16x32_bf16(
                        af[mi], bfr[ni], acc[mi][ni], 0, 0, 0);
        }
        __syncthreads();
    }

    // epilogue: C/D layout col=lane&15, row=quad*4+reg  (unchanged)
    #pragma unroll
    for (int mi = 0; mi < 4; mi++) {
        const int r0 = tm0 + wm + mi * 16 + quad * 4;
        #pragma unroll
        for (int ni = 0; ni < 4; ni++) {
            const int c = tn0 + wn + ni * 16 + l16;
            f32x4 v = acc[mi][ni];
            #pragma unroll
            for (int r = 0; r < 4; r++) Cb[(size_t)(r0 + r) * DD + c] = v[r];
        }
    }
}

// ---------------------------------------------------------------------------
extern "C" void kernel_launch(void* const* d_in, const int* in_sizes, int n_in,
                              void* d_out, int out_size, void* d_ws, size_t ws_size,
                              hipStream_t stream) {
    const float* sim = (const float*)d_in[0];   // [8, 2048, 1024]
    const float* qen = (const float*)d_in[1];   // [8, 1024, 1024]
    float* out = (float*)d_out;                 // [8, 2048, 1024]

    ushort* qt = (ushort*)d_ws;                                   // 16 MiB bf16
    float2* stats = (float2*)((char*)d_ws + (size_t)BATCH * DD * TQ * 2);  // 128 KiB

    rowstats<<<BATCH * TC / 8, 256, 0, stream>>>(sim, stats);
    transp<<<BATCH * (TQ / 64) * (DD / 128), 256, 0, stream>>>(qen, qt);
    gemm_fused<<<BATCH * (TC / 128) * (DD / 128), 256, 0, stream>>>(sim, stats, qt, out);
}

// Round 4
// 177.670 us; speedup vs baseline: 1.1883x; 1.1883x over previous
//
#include <hip/hip_runtime.h>
#include <hip/hip_bf16.h>
#include <stdint.h>

// Problem constants (from reference setup_inputs)
#define BATCH 8
#define TC 2048   // M
#define TQ 1024   // K
#define DD 1024   // N

typedef __attribute__((ext_vector_type(8))) __bf16 bf16x8;
typedef __attribute__((ext_vector_type(4))) float f32x4;
typedef __attribute__((ext_vector_type(8))) ushort ushort8v;

__device__ __forceinline__ ushort f2bf(float f) {
    uint32_t u = __float_as_uint(f);
    uint32_t r = (u + 0x7fffu + ((u >> 16) & 1u)) >> 16;  // RNE
    return (ushort)r;
}

// ---------------------------------------------------------------------------
// Kernel 1: softmax (full) -> bf16 attn.  R3-rowstats structure (proven ~6
// TB/s): 2 rows per wave, 8 float4 loads in flight, 0 LDS, homogeneous grid.
// exp overwrites x in-place (VGPR ~50 -> full occupancy).  Per-row reduction
// trees and per-element expressions are BIT-IDENTICAL to the original prep
// softmax -> attn values unchanged -> absmax must stay 0.001953125.
// ---------------------------------------------------------------------------
__global__ __launch_bounds__(256) void softmax2(const float* __restrict__ sim,
                                                ushort* __restrict__ attn) {
    const int t = threadIdx.x;
    const int wid = t >> 6, lane = t & 63;
    const int r0 = blockIdx.x * 8 + wid * 2;   // 4 waves x 2 rows = 8 rows/block

    const float4* s0 = (const float4*)(sim + (size_t)r0 * TQ);
    const float4* s1 = (const float4*)(sim + (size_t)(r0 + 1) * TQ);

    float4 x0[4], x1[4];
    #pragma unroll
    for (int j = 0; j < 4; j++) { x0[j] = s0[lane + 64 * j]; x1[j] = s1[lane + 64 * j]; }

    float m0 = -INFINITY, m1 = -INFINITY;
    #pragma unroll
    for (int j = 0; j < 4; j++) {
        m0 = fmaxf(m0, fmaxf(fmaxf(x0[j].x, x0[j].y), fmaxf(x0[j].z, x0[j].w)));
        m1 = fmaxf(m1, fmaxf(fmaxf(x1[j].x, x1[j].y), fmaxf(x1[j].z, x1[j].w)));
    }
    #pragma unroll
    for (int o = 32; o >= 1; o >>= 1) {
        m0 = fmaxf(m0, __shfl_xor(m0, o));
        m1 = fmaxf(m1, __shfl_xor(m1, o));
    }

    const float L2E = 1.4426950408889634f;
    float sa = 0.f, sb = 0.f;
    #pragma unroll
    for (int j = 0; j < 4; j++) {
        x0[j].x = exp2f((x0[j].x - m0) * L2E);
        x0[j].y = exp2f((x0[j].y - m0) * L2E);
        x0[j].z = exp2f((x0[j].z - m0) * L2E);
        x0[j].w = exp2f((x0[j].w - m0) * L2E);
        sa += (x0[j].x + x0[j].y) + (x0[j].z + x0[j].w);
        x1[j].x = exp2f((x1[j].x - m1) * L2E);
        x1[j].y = exp2f((x1[j].y - m1) * L2E);
        x1[j].z = exp2f((x1[j].z - m1) * L2E);
        x1[j].w = exp2f((x1[j].w - m1) * L2E);
        sb += (x1[j].x + x1[j].y) + (x1[j].z + x1[j].w);
    }
    #pragma unroll
    for (int o = 32; o >= 1; o >>= 1) {
        sa += __shfl_xor(sa, o);
        sb += __shfl_xor(sb, o);
    }
    const float iva = 1.0f / sa, ivb = 1.0f / sb;

    ushort4* d0 = (ushort4*)(attn + (size_t)r0 * TQ);
    ushort4* d1 = (ushort4*)(attn + (size_t)(r0 + 1) * TQ);
    #pragma unroll
    for (int j = 0; j < 4; j++) {
        ushort4 o4;
        o4.x = f2bf(x0[j].x * iva);
        o4.y = f2bf(x0[j].y * iva);
        o4.z = f2bf(x0[j].z * iva);
        o4.w = f2bf(x0[j].w * iva);
        d0[lane + 64 * j] = o4;
        o4.x = f2bf(x1[j].x * ivb);
        o4.y = f2bf(x1[j].y * ivb);
        o4.z = f2bf(x1[j].z * ivb);
        o4.w = f2bf(x1[j].w * ivb);
        d1[lane + 64 * j] = o4;
    }
}

// ---------------------------------------------------------------------------
// Kernel 2: transpose+cast  qencode [b][q][d] fp32 -> qt [b][d][q] bf16.
// (R3 kernel verbatim; proven ~6 TB/s in aggregate with rowstats.)
// ---------------------------------------------------------------------------
__global__ __launch_bounds__(256) void transp(const float* __restrict__ qen,
                                              ushort* __restrict__ qt) {
    __shared__ float tile[64][133];
    const int t = threadIdx.x;
    const int bid = blockIdx.x;
    const int b = bid >> 7;             // 128 tiles per batch (16 q x 8 d)
    const int rem = bid & 127;
    const int q0 = (rem >> 3) * 64;
    const int d0 = (rem & 7) * 128;

    const int r0 = t >> 5;              // 0..7
    const int cf = (t & 31) * 4;        // 0..124

    float4 v[8];
    #pragma unroll
    for (int it = 0; it < 8; it++)
        v[it] = *(const float4*)(qen + ((size_t)b * TQ + q0 + r0 + it * 8) * DD + d0 + cf);
    #pragma unroll
    for (int it = 0; it < 8; it++) {
        tile[r0 + it * 8][cf + 0] = v[it].x;
        tile[r0 + it * 8][cf + 1] = v[it].y;
        tile[r0 + it * 8][cf + 2] = v[it].z;
        tile[r0 + it * 8][cf + 3] = v[it].w;
    }
    __syncthreads();

    const int q8 = (t & 7) * 8;         // 0..56
    const int dbase = t >> 3;           // 0..31
    #pragma unroll
    for (int j2 = 0; j2 < 4; j2++) {
        const int d = dbase + 32 * j2;
        ushort8v pk;
        #pragma unroll
        for (int j = 0; j < 8; j++) pk[j] = f2bf(tile[q8 + j][d]);
        *(ushort8v*)(qt + ((size_t)b * DD + d0 + d) * TQ + q0 + q8) = pk;
    }
}

// ---------------------------------------------------------------------------
// Kernel 3: batched GEMM  C[b] = A[b] (MxK bf16) x Bt[b]^T (NxK bf16)
// EXACTLY the proven R0 kernel (43.6us) except the block-id decode:
//   b = flat & 7, rem = flat >> 3   (was b = flat>>7, rem = flat&127)
// -> HW round-robin dispatch (wg%8 -> XCD) gives each XCD one batch; its L2
// then holds only that batch's attn/qt panels (R2 evidence: FETCH 66->25 MB).
// Everything else (staging swizzle, MFMA order, epilogue) is untouched.
// ---------------------------------------------------------------------------
__global__ __launch_bounds__(256, 2) void gemm_bf16(const ushort* __restrict__ A,
                                                    const ushort* __restrict__ Bt,
                                                    float* __restrict__ C) {
    __shared__ __align__(16) ushort As[128 * 64];   // 16 KiB
    __shared__ __align__(16) ushort Bs[128 * 64];   // 16 KiB

    const int flat = blockIdx.x;
    const int b = flat & 7;           // batch = XCD (dispatch round-robin)
    const int rem = flat >> 3;        // 0..127: 16 m-tiles x 8 n-tiles
    const int group = rem >> 5;       // 4 groups of 32 blocks
    const int mi_t = group * 4 + (rem & 3);
    const int ni_t = (rem >> 2) & 7;
    const int tm0 = mi_t * 128;
    const int tn0 = ni_t * 128;

    const ushort* Ab = A + (size_t)b * TC * TQ;
    const ushort* Bb = Bt + (size_t)b * DD * TQ;
    float* Cb = C + (size_t)b * TC * DD;

    const int t = threadIdx.x;
    const int w = t >> 6, lane = t & 63;
    const int quad = lane >> 4, l16 = lane & 15;
    const int wm = (w >> 1) * 64, wn = (w & 1) * 64;

    f32x4 acc[4][4];
    #pragma unroll
    for (int i = 0; i < 4; i++)
        #pragma unroll
        for (int j = 0; j < 4; j++) acc[i][j] = (f32x4){0.f, 0.f, 0.f, 0.f};

    // staging: chunk idx = i*256 + w*64 + lane; row = idx>>3 = i*32+w*8+(lane>>3)
    // slot-chunk xs = lane&7; fetch global chunk c = xs ^ (row&7)
    const int srow = w * 8 + (lane >> 3);
    const int sk = ((lane & 7) ^ (lane >> 3)) * 8;   // ushort offset in k

    // fragment read: row = frag_base + l16 (frag_base % 16 == 0), so row&7 = l16&7
    const int rkey = l16 & 7;

    for (int kk = 0; kk < TQ; kk += 64) {
        #pragma unroll
        for (int i = 0; i < 4; i++) {
            const ushort* ga = Ab + (size_t)(tm0 + i * 32 + srow) * TQ + kk + sk;
            const ushort* gb = Bb + (size_t)(tn0 + i * 32 + srow) * TQ + kk + sk;
            char* la = (char*)As + i * 4096 + w * 1024;
            char* lb = (char*)Bs + i * 4096 + w * 1024;
            __builtin_amdgcn_global_load_lds(
                (const __attribute__((address_space(1))) void*)ga,
                (__attribute__((address_space(3))) void*)la, 16, 0, 0);
            __builtin_amdgcn_global_load_lds(
                (const __attribute__((address_space(1))) void*)gb,
                (__attribute__((address_space(3))) void*)lb, 16, 0, 0);
        }
        __syncthreads();

        #pragma unroll
        for (int s = 0; s < 2; s++) {
            const int rswz = ((s * 4 + quad) ^ rkey) * 8;   // ushort offset
            bf16x8 af[4], bfr[4];
            #pragma unroll
            for (int mi = 0; mi < 4; mi++)
                af[mi] = *(const bf16x8*)&As[(wm + mi * 16 + l16) * 64 + rswz];
            #pragma unroll
            for (int ni = 0; ni < 4; ni++)
                bfr[ni] = *(const bf16x8*)&Bs[(wn + ni * 16 + l16) * 64 + rswz];

            #pragma unroll
            for (int mi = 0; mi < 4; mi++)
                #pragma unroll
                for (int ni = 0; ni < 4; ni++)
                    acc[mi][ni] = __builtin_amdgcn_mfma_f32_16x16x32_bf16(
                        af[mi], bfr[ni], acc[mi][ni], 0, 0, 0);
        }
        __syncthreads();
    }

    // epilogue: C/D layout col=lane&15, row=quad*4+reg
    #pragma unroll
    for (int mi = 0; mi < 4; mi++) {
        const int r0 = tm0 + wm + mi * 16 + quad * 4;
        #pragma unroll
        for (int ni = 0; ni < 4; ni++) {
            const int c = tn0 + wn + ni * 16 + l16;
            f32x4 v = acc[mi][ni];
            #pragma unroll
            for (int r = 0; r < 4; r++) Cb[(size_t)(r0 + r) * DD + c] = v[r];
        }
    }
}

// ---------------------------------------------------------------------------
extern "C" void kernel_launch(void* const* d_in, const int* in_sizes, int n_in,
                              void* d_out, int out_size, void* d_ws, size_t ws_size,
                              hipStream_t stream) {
    const float* sim = (const float*)d_in[0];   // [8, 2048, 1024]
    const float* qen = (const float*)d_in[1];   // [8, 1024, 1024]
    float* out = (float*)d_out;                 // [8, 2048, 1024]

    ushort* attn = (ushort*)d_ws;                                  // 32 MiB bf16
    ushort* qt = (ushort*)d_ws + (size_t)BATCH * TC * TQ;          // 16 MiB bf16

    softmax2<<<BATCH * TC / 8, 256, 0, stream>>>(sim, attn);
    transp<<<BATCH * (TQ / 64) * (DD / 128), 256, 0, stream>>>(qen, qt);
    gemm_bf16<<<BATCH * (TC / 128) * (DD / 128), 256, 0, stream>>>(attn, qt, out);
}